// Round 1
// baseline (337.851 us; speedup 1.0000x reference)
//
#include <hip/hip_runtime.h>

typedef float v4f __attribute__((ext_vector_type(4)));

#define EPSF 1e-8f
#define HALF_PI 1.5707963267948966f
#define TWO_PI  6.283185307179586f

// image layout: (B=16, C=3, H*W = 1<<20), fp32.
// Each thread processes TWO float4 chunks (8 pixels), chunk indices tid and
// tid+half -> 6 independent nontemporal loads in flight per thread (2x MLP vs
// the 335us version), per-instruction coalescing unchanged (lane-contiguous 16B).
__device__ __forceinline__ void hvi4(v4f r4, v4f g4, v4f b4, float k,
                                     v4f& X, v4f& Y, v4f& Z)
{
#pragma unroll
    for (int j = 0; j < 4; ++j) {
        float r = r4[j], g = g4[j], b = b4[j];

        float v  = fmaxf(r, fmaxf(g, b));
        float mn = fminf(r, fminf(g, b));
        float denom = v - mn + EPSF;
        float invd = __builtin_amdgcn_rcpf(denom);   // ~2^-22 rel err, fine @2e-2 tol

        // hue candidates
        float hr = (g - b) * invd;                   // in (-1, 1)
        hr = (hr < 0.0f) ? hr + 6.0f : hr;           // == floor-mod 6 on (-1,1)
        float hg = 2.0f + (b - r) * invd;
        float hb = 4.0f + (r - g) * invd;

        // jnp.where chain, last-wins priority: min > r > g > b
        float hue = (b  == v) ? hb   : 0.0f;
        hue       = (g  == v) ? hg   : hue;
        hue       = (r  == v) ? hr   : hue;
        hue       = (mn == v) ? 0.0f : hue;
        hue *= (1.0f / 6.0f);

        float sat = (v == 0.0f) ? 0.0f
                                : (v - mn) * __builtin_amdgcn_rcpf(v + EPSF);

        // color_sensitive = (sin(v*pi/2) + eps)^k ; base > 0 always
        float cs = __powf(__sinf(v * HALF_PI) + EPSF, k);

        float ang = TWO_PI * hue;
        float s = cs * sat;
        X[j] = s * __cosf(ang);
        Y[j] = s * __sinf(ang);
        Z[j] = v;
    }
}

__global__ __launch_bounds__(256) void rgb2hvi_kernel(
    const float* __restrict__ img,
    const float* __restrict__ kptr,
    float* __restrict__ out,
    int n4, int half)   // n4 = pixels/4 (even here), half = n4/2
{
    int tid = blockIdx.x * blockDim.x + threadIdx.x;
    if (tid >= half) return;

    const float k = kptr[0];          // uniform -> scalar load
    const int HW = 1 << 20;           // 1024*1024

    // chunk A = tid, chunk B = tid + half. Max element offset 48M < 2^31 -> int math.
    int iA = tid << 2;
    int iB = (tid + half) << 2;
    int baseA = (iA >> 20) * (3 * HW) + (iA & (HW - 1));
    int baseB = (iB >> 20) * (3 * HW) + (iB & (HW - 1));

    // issue all 6 loads before any compute; nt = streaming, no L2 allocate
    v4f rA = __builtin_nontemporal_load((const v4f*)(img + baseA));
    v4f gA = __builtin_nontemporal_load((const v4f*)(img + baseA + HW));
    v4f bA = __builtin_nontemporal_load((const v4f*)(img + baseA + 2 * HW));
    v4f rB = __builtin_nontemporal_load((const v4f*)(img + baseB));
    v4f gB = __builtin_nontemporal_load((const v4f*)(img + baseB + HW));
    v4f bB = __builtin_nontemporal_load((const v4f*)(img + baseB + 2 * HW));

    v4f XA, YA, ZA, XB, YB, ZB;
    hvi4(rA, gA, bA, k, XA, YA, ZA);
    hvi4(rB, gB, bB, k, XB, YB, ZB);

    __builtin_nontemporal_store(XA, (v4f*)(out + baseA));
    __builtin_nontemporal_store(YA, (v4f*)(out + baseA + HW));
    __builtin_nontemporal_store(ZA, (v4f*)(out + baseA + 2 * HW));
    __builtin_nontemporal_store(XB, (v4f*)(out + baseB));
    __builtin_nontemporal_store(YB, (v4f*)(out + baseB + HW));
    __builtin_nontemporal_store(ZB, (v4f*)(out + baseB + 2 * HW));
}

extern "C" void kernel_launch(void* const* d_in, const int* in_sizes, int n_in,
                              void* d_out, int out_size, void* d_ws, size_t ws_size,
                              hipStream_t stream) {
    const float* img  = (const float*)d_in[0];
    const float* kptr = (const float*)d_in[1];
    float* out = (float*)d_out;

    int total = in_sizes[0];          // 16*3*1024*1024
    int pixels = total / 3;           // 16*1024*1024
    int n4 = pixels / 4;              // 4194304
    int half = n4 / 2;                // 2097152 (n4 is even for this shape)

    int block = 256;
    int grid = (half + block - 1) / block;  // 8192
    rgb2hvi_kernel<<<grid, block, 0, stream>>>(img, kptr, out, n4, half);
}